// Round 3
// baseline (328.039 us; speedup 1.0000x reference)
//
#include <hip/hip_runtime.h>

#define B_TOTAL   8388608
#define NQUADS    (B_TOTAL / 4)          // 2097152
#define THREADS   256
#define BLOCKS    2048
#define NTHREADS  (BLOCKS * THREADS)     // 524288
#define UNROLL    (NQUADS / NTHREADS)    // 4 quads (16 samples) per thread

// d_ws layout: float sums[4] | unsigned int count
__global__ __launch_bounds__(THREADS, 4) void trading_loss_fused(
    const float* __restrict__ preds,    // [B,3]
    const int*   __restrict__ targets,  // [B]
    const float* __restrict__ pc,       // [B]
    const float* __restrict__ td,       // [B]
    float*        __restrict__ sums,    // [4], zeroed
    unsigned int* __restrict__ count,   // zeroed
    float*        __restrict__ out)
{
    const unsigned tid = blockIdx.x * THREADS + threadIdx.x;

    const float4* preds4 = reinterpret_cast<const float4*>(preds);
    const int4*   tg4    = reinterpret_cast<const int4*  >(targets);
    const float4* pc4    = reinterpret_cast<const float4*>(pc);
    const float4* td4    = reinterpret_cast<const float4*>(td);

    // -------- phase 1: issue ALL loads (24 × vec4 per thread) --------
    float4 A0[UNROLL], A1[UNROLL], A2[UNROLL];
    int4   T[UNROLL];
    float4 P[UNROLL], D[UNROLL];

    #pragma unroll
    for (int u = 0; u < UNROLL; ++u) {
        const unsigned q = u * NTHREADS + tid;   // coalesced per-u slice
        A0[u] = preds4[(size_t)q * 3 + 0];
        A1[u] = preds4[(size_t)q * 3 + 1];
        A2[u] = preds4[(size_t)q * 3 + 2];
        T[u]  = tg4[q];
        P[u]  = pc4[q];
        D[u]  = td4[q];
    }

    // -------- phase 2: compute --------
    float s_cew = 0.f, s_ce = 0.f, s_mw = 0.f, s_tr = 0.f;

    #pragma unroll
    for (int u = 0; u < UNROLL; ++u) {
        float p[12] = {A0[u].x, A0[u].y, A0[u].z, A0[u].w,
                       A1[u].x, A1[u].y, A1[u].z, A1[u].w,
                       A2[u].x, A2[u].y, A2[u].z, A2[u].w};
        int   tt[4]  = {T[u].x, T[u].y, T[u].z, T[u].w};
        float pcv[4] = {P[u].x, P[u].y, P[u].z, P[u].w};
        float tdv[4] = {D[u].x, D[u].y, D[u].z, D[u].w};

        #pragma unroll
        for (int j = 0; j < 4; ++j) {
            float p0 = p[j*3 + 0], p1 = p[j*3 + 1], p2 = p[j*3 + 2];
            float m  = fmaxf(fmaxf(p0, p1), p2);
            float e0 = __expf(p0 - m);
            float e1 = __expf(p1 - m);
            float e2 = __expf(p2 - m);
            float lse = __logf(e0 + e1 + e2);
            int   t  = tt[j];
            float pt = (t == 0) ? p0 : ((t == 1) ? p1 : p2);
            float ce = lse - (pt - m);            // -log_softmax[t]
            float aw = fabsf(pcv[j]);

            s_ce  += ce;
            s_cew += ce * aw;
            s_mw  += aw;
            bool aligned = (tdv[j] > 0.f && t == 2) || (tdv[j] < 0.f && t == 0);
            s_tr += aligned ? 1.0f : 0.0f;
        }
    }

    // -------- phase 3: wave butterfly + LDS block reduce --------
    #pragma unroll
    for (int off = 32; off >= 1; off >>= 1) {
        s_cew += __shfl_down(s_cew, off, 64);
        s_ce  += __shfl_down(s_ce , off, 64);
        s_mw  += __shfl_down(s_mw , off, 64);
        s_tr  += __shfl_down(s_tr , off, 64);
    }

    __shared__ float red[4][4];
    const int lane = threadIdx.x & 63;
    const int wave = threadIdx.x >> 6;
    if (lane == 0) {
        red[wave][0] = s_cew;
        red[wave][1] = s_ce;
        red[wave][2] = s_mw;
        red[wave][3] = s_tr;
    }
    __syncthreads();

    // -------- phase 4: per-block atomics + last-block finalize --------
    if (threadIdx.x == 0) {
        float r0 = red[0][0] + red[1][0] + red[2][0] + red[3][0];
        float r1 = red[0][1] + red[1][1] + red[2][1] + red[3][1];
        float r2 = red[0][2] + red[1][2] + red[2][2] + red[3][2];
        float r3 = red[0][3] + red[1][3] + red[2][3] + red[3][3];

        atomicAdd(&sums[0], r0);
        atomicAdd(&sums[1], r1);
        atomicAdd(&sums[2], r2);
        atomicAdd(&sums[3], r3);

        __threadfence();                       // release: sums visible before count
        unsigned old = atomicAdd(count, 1u);
        if (old == BLOCKS - 1) {
            // coherent reads via atomic RMW (+0.0f)
            float cew = atomicAdd(&sums[0], 0.0f);
            float ce  = atomicAdd(&sums[1], 0.0f);
            float mw  = atomicAdd(&sums[2], 0.0f);
            float tr  = atomicAdd(&sums[3], 0.0f);

            const float invB = 1.0f / (float)B_TOTAL;
            float cew_mean = cew * invB;             // mean(ce * |pc|)
            float ce_mean  = ce  * invB;             // mean(ce)
            float mw_mean  = mw  * invB + 1e-8f;     // mean(|pc|) + EPS
            float tr_mean  = -0.1f * tr * invB;      // mean(trend_alignment)
            out[0] = 0.85f * (cew_mean / mw_mean) + 0.15f * ce_mean + 0.1f * tr_mean;
        }
    }
}

extern "C" void kernel_launch(void* const* d_in, const int* in_sizes, int n_in,
                              void* d_out, int out_size, void* d_ws, size_t ws_size,
                              hipStream_t stream) {
    const float* preds   = (const float*)d_in[0];
    const int*   targets = (const int*  )d_in[1];
    const float* pc      = (const float*)d_in[2];
    const float* td      = (const float*)d_in[3];
    float* out  = (float*)d_out;
    float* sums = (float*)d_ws;
    unsigned int* count = (unsigned int*)((char*)d_ws + 4 * sizeof(float));

    // d_ws is poisoned 0xAA before every timed launch — zero accumulators + counter.
    hipMemsetAsync(d_ws, 0, 5 * sizeof(float), stream);

    trading_loss_fused<<<BLOCKS, THREADS, 0, stream>>>(preds, targets, pc, td,
                                                       sums, count, out);
}